// Round 7
// baseline (124.329 us; speedup 1.0000x reference)
//
#include <hip/hip_runtime.h>
#include <math.h>

#define B_ 16
#define N_ 1024
#define K_ 64
#define C_ 128
#define INV_T 14.285714285714286f  // 1/0.07
#define NBLK_MAIN 2048             // 8 rows per block (4 waves x 2 rows)

using f32x2 = __attribute__((ext_vector_type(2))) float;

__device__ __forceinline__ float waveReduceSum(float v) {
#pragma unroll
    for (int off = 32; off > 0; off >>= 1)
        v += __shfl_xor(v, off, 64);
    return v;
}

// Kernel 1: L2-normalize k rows -> fp8 e4m3 kn (2 MB, HW cvt). 16384 rows;
// wave per row, 4 rows/wave -> 1024 blocks. Also zeroes the infonce ticket
// (ws is re-poisoned to 0xAA before every launch).
__global__ __launch_bounds__(256) void knorm_kernel(
    const float* __restrict__ k, unsigned char* __restrict__ kn,
    unsigned* __restrict__ ticket) {
    if (blockIdx.x == 0 && threadIdx.x == 0) *ticket = 0u;
    const int lane = threadIdx.x & 63;
    const int wid  = threadIdx.x >> 6;
    const int base = blockIdx.x * 16 + wid * 4;
#pragma unroll
    for (int r = 0; r < 4; ++r) {
        const int row = base + r;
        const float2 v = *(const float2*)(k + (size_t)row * C_ + 2 * lane);
        const float ss = waveReduceSum(v.x * v.x + v.y * v.y);
        const float inv = 1.0f / fmaxf(sqrtf(ss), 1e-12f);
        const int pk = __builtin_amdgcn_cvt_pk_fp8_f32(v.x * inv, v.y * inv, 0, false);
        *(unsigned short*)(kn + (size_t)row * C_ + 2 * lane) =
            (unsigned short)(pk & 0xffff);
    }
}

// Kernel 2: one wave per q-row, 2 rows/wave. q is normalized IN-REGISTER from
// fp32 (no qn table): each lane holds q[s*16..s*16+15], q.q via 8 pk-FMA + 3
// intra-group shfls, scale folds in 1/T. fp8 gather: one k-row = one 128B
// line; 8 lanes cover it with one uint4 load. 9 passes: 0-7 = 64 negatives
// (one row per 8-lane group), pass 8 = positive (all lanes, 1 line). LSE
// reductions need only the 3 cross-group xor levels (sims duplicated within
// groups). Tail: per-block partials + ticket; last block reduces and writes
// the final scalar (finalize kernel fused away).
__global__ __launch_bounds__(256, 4) void infonce_kernel(
    const float* __restrict__ q, const unsigned char* __restrict__ kn,
    const int* __restrict__ pos_idx, const int* __restrict__ neg_idx,
    float* __restrict__ partials, unsigned* __restrict__ ticket,
    float* __restrict__ out) {
    __shared__ float wave_tot[4], wave_cnt[4];
    __shared__ float st[256], sc2[256];
    __shared__ unsigned is_last;

    const int lane = threadIdx.x & 63;
    const int wid  = threadIdx.x >> 6;
    const int g    = lane >> 3;   // group 0..7
    const int s    = lane & 7;    // sub-lane within group

    const int batch = blockIdx.x & 15;   // XCD-affine batch mapping
    const int chunk = blockIdx.x >> 4;
    const int rbase = chunk * 8 + wid * 2;

    const unsigned char* kb = kn + (size_t)batch * (N_ * C_);

    float tot = 0.0f, cnt = 0.0f;

#pragma unroll
    for (int r = 0; r < 2; ++r) {
        const int n   = rbase + r;
        const int row = batch * N_ + n;

        // Load this lane's 16 q elems (fp32), compute q.q, scale by inv_q/T.
        const float* qrow = q + (size_t)row * C_;
        f32x2 qf[8];
        f32x2 qacc = f32x2{0.0f, 0.0f};
#pragma unroll
        for (int i = 0; i < 4; ++i) {
            const float4 v = *(const float4*)(qrow + s * 16 + i * 4);
            qf[i*2+0] = f32x2{v.x, v.y};
            qf[i*2+1] = f32x2{v.z, v.w};
            qacc = qf[i*2+0] * qf[i*2+0] + qacc;
            qacc = qf[i*2+1] * qf[i*2+1] + qacc;
        }
        float qss = qacc[0] + qacc[1];
        qss += __shfl_xor(qss, 1, 64);   // full row sum within each group
        qss += __shfl_xor(qss, 2, 64);
        qss += __shfl_xor(qss, 4, 64);
        const float sc = (1.0f / fmaxf(sqrtf(qss), 1e-12f)) * INV_T;
        const f32x2 scv = f32x2{sc, sc};
#pragma unroll
        for (int i = 0; i < 8; ++i) qf[i] *= scv;

        const int  pidx = pos_idx[row];     // wave-uniform
        const bool pval = pidx >= 0;
        const int  p0   = pval ? pidx : 0;

        // Group g's 8 negative indices (256B row, L1-hot).
        const int* nrow = neg_idx + (size_t)row * K_;
        int nidx[8];
#pragma unroll
        for (int p = 0; p < 8; ++p) nidx[p] = nrow[p * 8 + g];

        float d[9];
#pragma unroll
        for (int p = 0; p < 9; ++p) {
            const unsigned char* kr =
                (p < 8) ? kb + (size_t)(nidx[p] >= 0 ? nidx[p] : 0) * C_
                        : kb + (size_t)p0 * C_;
            const uint4 ku = *(const uint4*)(kr + s * 16);  // 16 fp8 elems
            const unsigned w[4] = {ku.x, ku.y, ku.z, ku.w};
            f32x2 acc = f32x2{0.0f, 0.0f};
#pragma unroll
            for (int i = 0; i < 4; ++i) {
                const f32x2 lo = __builtin_amdgcn_cvt_pk_f32_fp8(w[i], false);
                const f32x2 hi = __builtin_amdgcn_cvt_pk_f32_fp8(w[i], true);
                acc = lo * qf[i*2+0] + acc;   // v_pk_fma_f32
                acc = hi * qf[i*2+1] + acc;
            }
            float dot = acc[0] + acc[1];
            dot += __shfl_xor(dot, 1, 64);   // intra-group: DPP-fast
            dot += __shfl_xor(dot, 2, 64);
            dot += __shfl_xor(dot, 4, 64);
            d[p] = dot;                       // == logit (1/T pre-folded)
        }

        const float pos_sim = d[8];           // wave-uniform

        float simv[8];
#pragma unroll
        for (int p = 0; p < 8; ++p)
            simv[p] = (nidx[p] >= 0) ? d[p] : -INFINITY;

        float m = pos_sim;
#pragma unroll
        for (int p = 0; p < 8; ++p) m = fmaxf(m, simv[p]);
        m = fmaxf(m, __shfl_xor(m, 8, 64));
        m = fmaxf(m, __shfl_xor(m, 16, 64));
        m = fmaxf(m, __shfl_xor(m, 32, 64));

        float ssum = 0.0f;
#pragma unroll
        for (int p = 0; p < 8; ++p) ssum += __expf(simv[p] - m);
        ssum += __shfl_xor(ssum, 8, 64);
        ssum += __shfl_xor(ssum, 16, 64);
        ssum += __shfl_xor(ssum, 32, 64);
        ssum += __expf(pos_sim - m);

        const float per_patch = m + __logf(ssum) - pos_sim;
        if (pval) { tot += per_patch; cnt += 1.0f; }
    }

    if (lane == 0) { wave_tot[wid] = tot; wave_cnt[wid] = cnt; }
    __syncthreads();
    if (threadIdx.x == 0) {
        partials[2 * blockIdx.x]     = wave_tot[0] + wave_tot[1] + wave_tot[2] + wave_tot[3];
        partials[2 * blockIdx.x + 1] = wave_cnt[0] + wave_cnt[1] + wave_cnt[2] + wave_cnt[3];
        __threadfence();                               // publish partials
        const unsigned old = atomicAdd(ticket, 1u);    // device-scope
        is_last = (old == NBLK_MAIN - 1) ? 1u : 0u;
    }
    __syncthreads();

    if (is_last) {
        __threadfence();  // acquire all published partials
        float t = 0.0f, c = 0.0f;
        for (int i = threadIdx.x; i < NBLK_MAIN; i += 256) {
            t += partials[2 * i];
            c += partials[2 * i + 1];
        }
        st[threadIdx.x]  = t;
        sc2[threadIdx.x] = c;
        __syncthreads();
        for (int off = 128; off > 0; off >>= 1) {
            if (threadIdx.x < off) {
                st[threadIdx.x]  += st[threadIdx.x + off];
                sc2[threadIdx.x] += sc2[threadIdx.x + off];
            }
            __syncthreads();
        }
        if (threadIdx.x == 0) {
            const float cntv = sc2[0];
            out[0] = (cntv > 0.0f) ? st[0] / fmaxf(cntv, 1.0f) : 0.0f;
        }
    }
}

extern "C" void kernel_launch(void* const* d_in, const int* in_sizes, int n_in,
                              void* d_out, int out_size, void* d_ws, size_t ws_size,
                              hipStream_t stream) {
    const float* q   = (const float*)d_in[0];
    const float* k   = (const float*)d_in[1];
    const int*   pos = (const int*)d_in[2];
    const int*   neg = (const int*)d_in[3];
    float* out = (float*)d_out;

    float* wsf = (float*)d_ws;
    float*    partials = wsf;                          // 4096 floats
    unsigned* ticket   = (unsigned*)(wsf + 4096);      // 1 word
    unsigned char* kn  = (unsigned char*)(wsf + 8192); // 2 MB (fp8)

    knorm_kernel<<<1024, 256, 0, stream>>>(k, kn, ticket);
    infonce_kernel<<<NBLK_MAIN, 256, 0, stream>>>(q, kn, pos, neg,
                                                  partials, ticket, out);
}

// Round 8
// 87.934 us; speedup vs baseline: 1.4139x; 1.4139x over previous
//
#include <hip/hip_runtime.h>
#include <math.h>

#define B_ 16
#define N_ 1024
#define K_ 64
#define C_ 128
#define INV_T 14.285714285714286f  // 1/0.07
#define NBLK_MAIN 2048             // 8 rows per block (4 waves x 2 rows)

using f32x2 = __attribute__((ext_vector_type(2))) float;

__device__ __forceinline__ float waveReduceSum(float v) {
#pragma unroll
    for (int off = 32; off > 0; off >>= 1)
        v += __shfl_xor(v, off, 64);
    return v;
}

// Kernel 1: L2-normalize k rows -> fp8 e4m3 kn (2 MB, HW cvt). 16384 rows;
// wave per row, 4 rows/wave -> 1024 blocks.
// NOTE (R7 post-mortem): do NOT fuse the final reduction into the gather
// kernel with a ticket + __threadfence — device-scope release fences on
// gfx950 invalidate/write back per-XCD L2 and destroy kn's L2 residency
// (infonce went 13 -> 65 us). Separate tiny finalize kernel is cheaper.
__global__ __launch_bounds__(256) void knorm_kernel(
    const float* __restrict__ k, unsigned char* __restrict__ kn) {
    const int lane = threadIdx.x & 63;
    const int wid  = threadIdx.x >> 6;
    const int base = blockIdx.x * 16 + wid * 4;
#pragma unroll
    for (int r = 0; r < 4; ++r) {
        const int row = base + r;
        const float2 v = *(const float2*)(k + (size_t)row * C_ + 2 * lane);
        const float ss = waveReduceSum(v.x * v.x + v.y * v.y);
        const float inv = 1.0f / fmaxf(sqrtf(ss), 1e-12f);
        const int pk = __builtin_amdgcn_cvt_pk_fp8_f32(v.x * inv, v.y * inv, 0, false);
        *(unsigned short*)(kn + (size_t)row * C_ + 2 * lane) =
            (unsigned short)(pk & 0xffff);
    }
}

// Kernel 2: one wave per q-row, 2 rows/wave. q normalized IN-REGISTER from
// fp32 (no qn table): lane holds q[s*16..s*16+15], q.q via 8 pk-FMA + 3
// intra-group shfls; scale folds in 1/T. fp8 gather: one k-row = one 128B
// line; 8 lanes cover it with one uint4 load. 9 passes: 0-7 = 64 negatives
// (one row per 8-lane group), pass 8 = positive (all lanes, 1 line). LSE
// reductions need only the 3 cross-group xor levels (sims duplicated within
// each group's 8 lanes).
__global__ __launch_bounds__(256, 4) void infonce_kernel(
    const float* __restrict__ q, const unsigned char* __restrict__ kn,
    const int* __restrict__ pos_idx, const int* __restrict__ neg_idx,
    float* __restrict__ partials) {
    __shared__ float wave_tot[4], wave_cnt[4];

    const int lane = threadIdx.x & 63;
    const int wid  = threadIdx.x >> 6;
    const int g    = lane >> 3;   // group 0..7
    const int s    = lane & 7;    // sub-lane within group

    const int batch = blockIdx.x & 15;   // XCD-affine batch mapping
    const int chunk = blockIdx.x >> 4;
    const int rbase = chunk * 8 + wid * 2;

    const unsigned char* kb = kn + (size_t)batch * (N_ * C_);

    float tot = 0.0f, cnt = 0.0f;

#pragma unroll
    for (int r = 0; r < 2; ++r) {
        const int n   = rbase + r;
        const int row = batch * N_ + n;

        // Load this lane's 16 q elems (fp32), compute q.q, scale by inv_q/T.
        const float* qrow = q + (size_t)row * C_;
        f32x2 qf[8];
        f32x2 qacc = f32x2{0.0f, 0.0f};
#pragma unroll
        for (int i = 0; i < 4; ++i) {
            const float4 v = *(const float4*)(qrow + s * 16 + i * 4);
            qf[i*2+0] = f32x2{v.x, v.y};
            qf[i*2+1] = f32x2{v.z, v.w};
            qacc = qf[i*2+0] * qf[i*2+0] + qacc;
            qacc = qf[i*2+1] * qf[i*2+1] + qacc;
        }
        float qss = qacc[0] + qacc[1];
        qss += __shfl_xor(qss, 1, 64);   // full row sum within each group
        qss += __shfl_xor(qss, 2, 64);
        qss += __shfl_xor(qss, 4, 64);
        const float sc = (1.0f / fmaxf(sqrtf(qss), 1e-12f)) * INV_T;
        const f32x2 scv = f32x2{sc, sc};
#pragma unroll
        for (int i = 0; i < 8; ++i) qf[i] *= scv;

        const int  pidx = pos_idx[row];     // wave-uniform
        const bool pval = pidx >= 0;
        const int  p0   = pval ? pidx : 0;

        // Group g's 8 negative indices (256B row, L1-hot).
        const int* nrow = neg_idx + (size_t)row * K_;
        int nidx[8];
#pragma unroll
        for (int p = 0; p < 8; ++p) nidx[p] = nrow[p * 8 + g];

        float d[9];
#pragma unroll
        for (int p = 0; p < 9; ++p) {
            const unsigned char* kr =
                (p < 8) ? kb + (size_t)(nidx[p] >= 0 ? nidx[p] : 0) * C_
                        : kb + (size_t)p0 * C_;
            const uint4 ku = *(const uint4*)(kr + s * 16);  // 16 fp8 elems
            const unsigned w[4] = {ku.x, ku.y, ku.z, ku.w};
            f32x2 acc = f32x2{0.0f, 0.0f};
#pragma unroll
            for (int i = 0; i < 4; ++i) {
                const f32x2 lo = __builtin_amdgcn_cvt_pk_f32_fp8(w[i], false);
                const f32x2 hi = __builtin_amdgcn_cvt_pk_f32_fp8(w[i], true);
                acc = lo * qf[i*2+0] + acc;   // v_pk_fma_f32
                acc = hi * qf[i*2+1] + acc;
            }
            float dot = acc[0] + acc[1];
            dot += __shfl_xor(dot, 1, 64);   // intra-group: DPP-fast
            dot += __shfl_xor(dot, 2, 64);
            dot += __shfl_xor(dot, 4, 64);
            d[p] = dot;                       // == logit (1/T pre-folded)
        }

        const float pos_sim = d[8];           // wave-uniform

        float simv[8];
#pragma unroll
        for (int p = 0; p < 8; ++p)
            simv[p] = (nidx[p] >= 0) ? d[p] : -INFINITY;

        float m = pos_sim;
#pragma unroll
        for (int p = 0; p < 8; ++p) m = fmaxf(m, simv[p]);
        m = fmaxf(m, __shfl_xor(m, 8, 64));
        m = fmaxf(m, __shfl_xor(m, 16, 64));
        m = fmaxf(m, __shfl_xor(m, 32, 64));

        float ssum = 0.0f;
#pragma unroll
        for (int p = 0; p < 8; ++p) ssum += __expf(simv[p] - m);
        ssum += __shfl_xor(ssum, 8, 64);
        ssum += __shfl_xor(ssum, 16, 64);
        ssum += __shfl_xor(ssum, 32, 64);
        ssum += __expf(pos_sim - m);

        const float per_patch = m + __logf(ssum) - pos_sim;
        if (pval) { tot += per_patch; cnt += 1.0f; }
    }

    if (lane == 0) { wave_tot[wid] = tot; wave_cnt[wid] = cnt; }
    __syncthreads();
    if (threadIdx.x == 0) {
        partials[2 * blockIdx.x]     = wave_tot[0] + wave_tot[1] + wave_tot[2] + wave_tot[3];
        partials[2 * blockIdx.x + 1] = wave_cnt[0] + wave_cnt[1] + wave_cnt[2] + wave_cnt[3];
    }
}

// Kernel 3: reduce block partials, emit total / count.
__global__ __launch_bounds__(256) void finalize_kernel(const float* __restrict__ partials,
                                                       float* __restrict__ out, int nblocks) {
    __shared__ float st[256], sc[256];
    float t = 0.0f, c = 0.0f;
    for (int i = threadIdx.x; i < nblocks; i += 256) {
        t += partials[2 * i];
        c += partials[2 * i + 1];
    }
    st[threadIdx.x] = t;
    sc[threadIdx.x] = c;
    __syncthreads();
    for (int off = 128; off > 0; off >>= 1) {
        if (threadIdx.x < off) {
            st[threadIdx.x] += st[threadIdx.x + off];
            sc[threadIdx.x] += sc[threadIdx.x + off];
        }
        __syncthreads();
    }
    if (threadIdx.x == 0) {
        const float cntv = sc[0];
        out[0] = (cntv > 0.0f) ? st[0] / fmaxf(cntv, 1.0f) : 0.0f;
    }
}

extern "C" void kernel_launch(void* const* d_in, const int* in_sizes, int n_in,
                              void* d_out, int out_size, void* d_ws, size_t ws_size,
                              hipStream_t stream) {
    const float* q   = (const float*)d_in[0];
    const float* k   = (const float*)d_in[1];
    const int*   pos = (const int*)d_in[2];
    const int*   neg = (const int*)d_in[3];
    float* out = (float*)d_out;

    float* wsf = (float*)d_ws;
    float*         partials = wsf;                      // 4096 floats
    unsigned char* kn = (unsigned char*)(wsf + 8192);   // 2 MB (fp8)

    knorm_kernel<<<1024, 256, 0, stream>>>(k, kn);
    infonce_kernel<<<NBLK_MAIN, 256, 0, stream>>>(q, kn, pos, neg, partials);
    finalize_kernel<<<1, 256, 0, stream>>>(partials, out, NBLK_MAIN);
}

// Round 9
// 86.290 us; speedup vs baseline: 1.4408x; 1.0191x over previous
//
#include <hip/hip_runtime.h>
#include <math.h>

#define B_ 16
#define N_ 1024
#define K_ 64
#define C_ 128
#define INV_T 14.285714285714286f  // 1/0.07
#define NBLK_MAIN 2048             // 8 rows per block (4 waves x 2 rows)

using f32x2 = __attribute__((ext_vector_type(2))) float;

__device__ __forceinline__ float waveReduceSum(float v) {
#pragma unroll
    for (int off = 32; off > 0; off >>= 1)
        v += __shfl_xor(v, off, 64);
    return v;
}

// fp32 -> bf16 round-to-nearest-even (finite normals only).
__device__ __forceinline__ unsigned short f2bf(float x) {
    unsigned u = __float_as_uint(x);
    return (unsigned short)((u + 0x7fffu + ((u >> 16) & 1u)) >> 16);
}
__device__ __forceinline__ float bflo(unsigned u) { return __uint_as_float(u << 16); }
__device__ __forceinline__ float bfhi(unsigned u) { return __uint_as_float(u & 0xffff0000u); }

// Kernel 1: L2-normalize. q rows -> bf16 qn PRE-SCALED by 1/T (4 MB);
// k rows -> fp8 e4m3 kn (2 MB, HW cvt). Wave per row, 4 rows/wave.
// R8 lesson: keeping q as a bf16 table beats re-reading fp32 q in the gather
// kernel (8 MB HBM stream + in-reg norm cost ~+1.7 us).
// R7 lesson: never fuse the final reduction into the gather kernel with
// ticket+__threadfence — device-scope release fences invalidate per-XCD L2
// and destroyed kn residency (13 -> 65 us).
__global__ __launch_bounds__(256) void normalize_kernel(
    const float* __restrict__ q, const float* __restrict__ k,
    unsigned short* __restrict__ qn, unsigned char* __restrict__ kn) {
    const int lane = threadIdx.x & 63;
    const int wid  = threadIdx.x >> 6;
    const int base = blockIdx.x * 16 + wid * 4;
#pragma unroll
    for (int r = 0; r < 4; ++r) {
        const int row = base + r;                     // 0..32767
        const bool is_q = row < (B_ * N_);
        const int  rr   = is_q ? row : row - B_ * N_;
        const float* src = (is_q ? q : k) + (size_t)rr * C_;
        const float2 v = *(const float2*)(src + 2 * lane);
        const float ss = waveReduceSum(v.x * v.x + v.y * v.y);
        const float inv = 1.0f / fmaxf(sqrtf(ss), 1e-12f);
        if (is_q) {
            const float sc = inv * INV_T;             // fold 1/T into q
            ushort2 o; o.x = f2bf(v.x * sc); o.y = f2bf(v.y * sc);
            *(ushort2*)(qn + (size_t)rr * C_ + 2 * lane) = o;
        } else {
            const int pk = __builtin_amdgcn_cvt_pk_fp8_f32(v.x * inv, v.y * inv, 0, false);
            *(unsigned short*)(kn + (size_t)rr * C_ + 2 * lane) =
                (unsigned short)(pk & 0xffff);
        }
    }
}

// Kernel 2: one wave per q-row, 2 rows/wave. fp8 gather: one k-row = one
// 128B line; 8 lanes cover it with a single uint4 load. 9 passes: 0-7 = 64
// negatives (one row per 8-lane group), pass 8 = positive (all lanes, 1
// line). R9: idx loads hoisted first (head of the longest dep chain) and all
// 9 gather loads batch-issued into registers BEFORE any decode/FMA — raises
// per-wave outstanding VMEM from ~3 to ~9 to cover L2 latency (VGPR rises to
// ~90 -> 4 waves/SIMD; outstanding gathers/CU: 96 -> 144).
__global__ __launch_bounds__(256, 4) void infonce_kernel(
    const unsigned short* __restrict__ qn, const unsigned char* __restrict__ kn,
    const int* __restrict__ pos_idx, const int* __restrict__ neg_idx,
    float* __restrict__ partials) {
    __shared__ float wave_tot[4], wave_cnt[4];

    const int lane = threadIdx.x & 63;
    const int wid  = threadIdx.x >> 6;
    const int g    = lane >> 3;   // group 0..7
    const int s    = lane & 7;    // sub-lane within group

    const int batch = blockIdx.x & 15;   // XCD-affine batch mapping
    const int chunk = blockIdx.x >> 4;
    const int rbase = chunk * 8 + wid * 2;

    const unsigned char* kb = kn + (size_t)batch * (N_ * C_);

    float tot = 0.0f, cnt = 0.0f;

#pragma unroll
    for (int r = 0; r < 2; ++r) {
        const int n   = rbase + r;
        const int row = batch * N_ + n;

        // --- Phase 1: index loads (head of the critical chain) ---
        const int* nrow = neg_idx + (size_t)row * K_;
        int nidx[8];
#pragma unroll
        for (int p = 0; p < 8; ++p) nidx[p] = nrow[p * 8 + g];
        const int  pidx = pos_idx[row];     // wave-uniform
        const bool pval = pidx >= 0;
        const int  p0   = pval ? pidx : 0;

        // --- Phase 2: batch-issue all 9 gather loads (stay in flight) ---
        uint4 ku[9];
#pragma unroll
        for (int p = 0; p < 9; ++p) {
            const unsigned char* kr =
                (p < 8) ? kb + (size_t)(nidx[p] >= 0 ? nidx[p] : 0) * C_
                        : kb + (size_t)p0 * C_;
            ku[p] = *(const uint4*)(kr + s * 16);   // 16 fp8 elems
        }

        // --- Phase 3: q fragments (bf16 table, pre-scaled by 1/T) ---
        const unsigned short* qrow = qn + (size_t)row * C_;
        f32x2 qf[8];
#pragma unroll
        for (int i = 0; i < 2; ++i) {
            const uint4 qu = *(const uint4*)(qrow + s * 16 + i * 8);
            qf[i*4+0] = f32x2{bflo(qu.x), bfhi(qu.x)};
            qf[i*4+1] = f32x2{bflo(qu.y), bfhi(qu.y)};
            qf[i*4+2] = f32x2{bflo(qu.z), bfhi(qu.z)};
            qf[i*4+3] = f32x2{bflo(qu.w), bfhi(qu.w)};
        }

        // --- Phase 4: decode + dot + intra-group reduce per pass ---
        float d[9];
#pragma unroll
        for (int p = 0; p < 9; ++p) {
            const unsigned w[4] = {ku[p].x, ku[p].y, ku[p].z, ku[p].w};
            f32x2 acc = f32x2{0.0f, 0.0f};
#pragma unroll
            for (int i = 0; i < 4; ++i) {
                const f32x2 lo = __builtin_amdgcn_cvt_pk_f32_fp8(w[i], false);
                const f32x2 hi = __builtin_amdgcn_cvt_pk_f32_fp8(w[i], true);
                acc = lo * qf[i*2+0] + acc;   // v_pk_fma_f32
                acc = hi * qf[i*2+1] + acc;
            }
            float dot = acc[0] + acc[1];
            dot += __shfl_xor(dot, 1, 64);   // intra-group: DPP-fast
            dot += __shfl_xor(dot, 2, 64);
            dot += __shfl_xor(dot, 4, 64);
            d[p] = dot;                       // == logit (1/T pre-folded)
        }

        const float pos_sim = d[8];           // wave-uniform

        float simv[8];
#pragma unroll
        for (int p = 0; p < 8; ++p)
            simv[p] = (nidx[p] >= 0) ? d[p] : -INFINITY;

        // Max/sum need only the 3 cross-group xor levels (sims duplicated
        // across each group's 8 lanes).
        float m = pos_sim;
#pragma unroll
        for (int p = 0; p < 8; ++p) m = fmaxf(m, simv[p]);
        m = fmaxf(m, __shfl_xor(m, 8, 64));
        m = fmaxf(m, __shfl_xor(m, 16, 64));
        m = fmaxf(m, __shfl_xor(m, 32, 64));

        float ssum = 0.0f;
#pragma unroll
        for (int p = 0; p < 8; ++p) ssum += __expf(simv[p] - m);
        ssum += __shfl_xor(ssum, 8, 64);
        ssum += __shfl_xor(ssum, 16, 64);
        ssum += __shfl_xor(ssum, 32, 64);
        ssum += __expf(pos_sim - m);

        const float per_patch = m + __logf(ssum) - pos_sim;
        if (pval) { tot += per_patch; cnt += 1.0f; }
    }

    if (lane == 0) { wave_tot[wid] = tot; wave_cnt[wid] = cnt; }
    __syncthreads();
    if (threadIdx.x == 0) {
        partials[2 * blockIdx.x]     = wave_tot[0] + wave_tot[1] + wave_tot[2] + wave_tot[3];
        partials[2 * blockIdx.x + 1] = wave_cnt[0] + wave_cnt[1] + wave_cnt[2] + wave_cnt[3];
    }
}

// Kernel 3: reduce block partials, emit total / count.
__global__ __launch_bounds__(256) void finalize_kernel(const float* __restrict__ partials,
                                                       float* __restrict__ out, int nblocks) {
    __shared__ float st[256], sc[256];
    float t = 0.0f, c = 0.0f;
    for (int i = threadIdx.x; i < nblocks; i += 256) {
        t += partials[2 * i];
        c += partials[2 * i + 1];
    }
    st[threadIdx.x] = t;
    sc[threadIdx.x] = c;
    __syncthreads();
    for (int off = 128; off > 0; off >>= 1) {
        if (threadIdx.x < off) {
            st[threadIdx.x] += st[threadIdx.x + off];
            sc[threadIdx.x] += sc[threadIdx.x + off];
        }
        __syncthreads();
    }
    if (threadIdx.x == 0) {
        const float cntv = sc[0];
        out[0] = (cntv > 0.0f) ? st[0] / fmaxf(cntv, 1.0f) : 0.0f;
    }
}

extern "C" void kernel_launch(void* const* d_in, const int* in_sizes, int n_in,
                              void* d_out, int out_size, void* d_ws, size_t ws_size,
                              hipStream_t stream) {
    const float* q   = (const float*)d_in[0];
    const float* k   = (const float*)d_in[1];
    const int*   pos = (const int*)d_in[2];
    const int*   neg = (const int*)d_in[3];
    float* out = (float*)d_out;

    float* wsf = (float*)d_ws;
    float* partials = wsf;                                   // 4096 floats
    unsigned short* qn = (unsigned short*)(wsf + 8192);      // 4 MB (bf16, pre-scaled)
    unsigned char*  kn = (unsigned char*)(qn + (size_t)B_ * N_ * C_);  // 2 MB (fp8)

    normalize_kernel<<<2048, 256, 0, stream>>>(q, k, qn, kn);
    infonce_kernel<<<NBLK_MAIN, 256, 0, stream>>>(qn, kn, pos, neg, partials);
    finalize_kernel<<<1, 256, 0, stream>>>(partials, out, NBLK_MAIN);
}